// Round 1
// baseline (252.743 us; speedup 1.0000x reference)
//
#include <hip/hip_runtime.h>
#include <math.h>

// Problem constants (from reference)
constexpr int IC   = 8;    // in channels
constexpr int OC   = 32;   // out channels
constexpr int KS   = 5;    // kernel size
constexpr int B_   = 16;   // batch
constexpr int HW_  = 128;  // H = W
constexpr int FH   = 124;  // output spatial (H - KS + 1)
constexpr int KTAP = KS * KS; // 25

// Transpose K from (O, C, 5, 5) to (C, 25, O) so that for a fixed (c, tap)
// the 32 output-channel values are contiguous -> compiler emits wide scalar
// loads (s_load_dwordx8/16) since the address is wave-uniform.
__global__ void transpose_k_kernel(const float* __restrict__ Kh,
                                   const float* __restrict__ Km,
                                   float* __restrict__ Kth,
                                   float* __restrict__ Ktm) {
    int idx = blockIdx.x * 256 + threadIdx.x;
    if (idx >= IC * KTAP * OC) return;
    int o  = idx & (OC - 1);
    int ct = idx >> 5;          // c*25 + t
    int t  = ct % KTAP;
    int c  = ct / KTAP;
    int src = (o * IC + c) * KTAP + t;
    Kth[idx] = Kh[src];
    Ktm[idx] = Km[src];
}

// One thread per (b, i, j); computes all 32 output channels.
// K reads are wave-uniform -> scalar loads into SGPRs (v_subrev_f32 v,s,v
// reads one SGPR per VALU op, legal). hit/miss accumulators stay in VGPRs
// with compile-time indices only (no scratch).
template<bool TRANS>
__global__ __launch_bounds__(128) void hitmiss_kernel(
    const float* __restrict__ x,
    const float* __restrict__ Kh,
    const float* __restrict__ Km,
    float* __restrict__ out)
{
    const int j = threadIdx.x;
    const int i = blockIdx.x;
    const int b = blockIdx.y;
    if (j >= FH) return;   // 4 idle lanes per wave; keeps all loads in-bounds

    float hit[OC], miss[OC];
#pragma unroll
    for (int o = 0; o < OC; ++o) { hit[o] = INFINITY; miss[o] = -INFINITY; }

#pragma unroll 1   // keep c-loop rolled: body ~20KB fits I-cache
    for (int c = 0; c < IC; ++c) {
        const float* xp = x + (((b * IC + c) * HW_) + i) * HW_ + j;
        float xw[KTAP];
#pragma unroll
        for (int u = 0; u < KS; ++u)
#pragma unroll
            for (int v = 0; v < KS; ++v)
                xw[u * KS + v] = xp[u * HW_ + v];   // L1-served, overlapping windows

        // Pair taps: 2 subs + 1 v_min3 fold two terms into the accumulator.
#pragma unroll
        for (int t = 0; t < KTAP - 1; t += 2) {
            const float x0 = xw[t], x1 = xw[t + 1];
#pragma unroll
            for (int o = 0; o < OC; ++o) {
                const float kh0 = TRANS ? Kh[(c * KTAP + t) * OC + o]
                                        : Kh[(o * IC + c) * KTAP + t];
                const float kh1 = TRANS ? Kh[(c * KTAP + t + 1) * OC + o]
                                        : Kh[(o * IC + c) * KTAP + t + 1];
                const float km0 = TRANS ? Km[(c * KTAP + t) * OC + o]
                                        : Km[(o * IC + c) * KTAP + t];
                const float km1 = TRANS ? Km[(c * KTAP + t + 1) * OC + o]
                                        : Km[(o * IC + c) * KTAP + t + 1];
                hit[o]  = fminf(fminf(x0 - kh0, x1 - kh1), hit[o]);   // -> v_min3_f32
                miss[o] = fmaxf(fmaxf(x0 - km0, x1 - km1), miss[o]);  // -> v_max3_f32
            }
        }
        {   // last (odd) tap, t = 24
            const float x0 = xw[KTAP - 1];
#pragma unroll
            for (int o = 0; o < OC; ++o) {
                const float kh0 = TRANS ? Kh[(c * KTAP + KTAP - 1) * OC + o]
                                        : Kh[(o * IC + c) * KTAP + KTAP - 1];
                const float km0 = TRANS ? Km[(c * KTAP + KTAP - 1) * OC + o]
                                        : Km[(o * IC + c) * KTAP + KTAP - 1];
                hit[o]  = fminf(hit[o],  x0 - kh0);
                miss[o] = fmaxf(miss[o], x0 - km0);
            }
        }
    }

    float* op = out + ((size_t)(b * OC) * FH + i) * FH + j;
#pragma unroll
    for (int o = 0; o < OC; ++o)
        op[(size_t)o * FH * FH] = hit[o] - miss[o];   // coalesced over j
}

extern "C" void kernel_launch(void* const* d_in, const int* in_sizes, int n_in,
                              void* d_out, int out_size, void* d_ws, size_t ws_size,
                              hipStream_t stream) {
    const float* x  = (const float*)d_in[0];
    const float* Kh = (const float*)d_in[1];
    const float* Km = (const float*)d_in[2];
    float* out = (float*)d_out;

    const size_t kelems = (size_t)IC * KTAP * OC; // 6400 floats per array
    dim3 grid(FH, B_);
    if (ws_size >= 2 * kelems * sizeof(float)) {
        float* Kth = (float*)d_ws;
        float* Ktm = Kth + kelems;
        transpose_k_kernel<<<(int)((kelems + 255) / 256), 256, 0, stream>>>(Kh, Km, Kth, Ktm);
        hitmiss_kernel<true><<<grid, 128, 0, stream>>>(x, Kth, Ktm, out);
    } else {
        // Fallback: read K in original (O,C,5,5) layout (strided scalar loads).
        hitmiss_kernel<false><<<grid, 128, 0, stream>>>(x, Kh, Km, out);
    }
}

// Round 4
// 168.700 us; speedup vs baseline: 1.4982x; 1.4982x over previous
//
#include <hip/hip_runtime.h>
#include <math.h>

// Problem constants (from reference)
constexpr int IC   = 8;    // in channels
constexpr int OC   = 32;   // out channels
constexpr int KS   = 5;    // kernel size
constexpr int B_   = 16;   // batch
constexpr int HW_  = 128;  // H = W
constexpr int FH   = 124;  // output spatial (H - KS + 1)
constexpr int KTAP = KS * KS; // 25
constexpr int OG   = 4;    // output-channel groups (blockIdx.z)
constexpr int OPG  = 8;    // output channels per group

typedef _Float16 h2 __attribute__((ext_vector_type(2)));

// ---------------------------------------------------------------------------
// Pack -K_hit / -K_miss into f16x2 broadcast pairs.
// Layout: Kpk[((c*OG+g)*KTAP + t)*16 + h*8 + oi], h=0 hit, h=1 miss.
// For fixed (c,g,t) the 16 dwords are contiguous -> one s_load_dwordx16/tap.
__global__ void pack_k_kernel(const float* __restrict__ Kh,
                              const float* __restrict__ Km,
                              unsigned* __restrict__ Kpk) {
    int idx = blockIdx.x * 256 + threadIdx.x;
    if (idx >= IC * OG * KTAP * 2 * OPG) return;   // 12800 dwords
    int oi = idx & 7;
    int h  = (idx >> 3) & 1;
    int t  = (idx >> 4) % KTAP;
    int cg = (idx >> 4) / KTAP;
    int g  = cg & (OG - 1), c = cg >> 2;
    int o  = g * OPG + oi;
    const float* K = h ? Km : Kh;
    float k = -K[(o * IC + c) * KTAP + t];
    _Float16 nk = (_Float16)k;
    unsigned short us = __builtin_bit_cast(unsigned short, nk);
    Kpk[idx] = (unsigned)us | ((unsigned)us << 16);
}

// ---------------------------------------------------------------------------
// Packed-f16 hit-or-miss. One lane = 2 adjacent output pixels (j0, j0+1),
// 8 output channels (group = blockIdx.z, wave-uniform -> K via s_load).
// Inner op: pk_min(pk_add(x_pk, -k_pk), acc) = 1 inst/tap/pixel per side.
__global__ __launch_bounds__(64, 6) void hitmiss_f16_kernel(
    const float* __restrict__ x,
    const unsigned* __restrict__ Kpk,
    float* __restrict__ out)
{
    const int lane = threadIdx.x;           // 0..63
    const int i = blockIdx.x, b = blockIdx.y, g = blockIdx.z;
    const int j0 = lane * 2;
    if (j0 >= FH) return;                   // lanes 62,63 idle; keeps loads in-bounds

    h2 hit[OPG], miss[OPG];
    const h2 pinf = {(_Float16)INFINITY, (_Float16)INFINITY};
    const h2 ninf = {(_Float16)(-INFINITY), (_Float16)(-INFINITY)};
#pragma unroll
    for (int oi = 0; oi < OPG; ++oi) { hit[oi] = pinf; miss[oi] = ninf; }

#pragma unroll 1   // keep c rolled: per-c body ~6KB fits I-cache
    for (int c = 0; c < IC; ++c) {
        const float* xp = x + (((b * IC + c) * HW_) + i) * HW_ + j0;
        h2 xpk[KTAP];   // xpk[t] = (x[j0+v], x[j0+1+v]) as f16x2
#pragma unroll
        for (int u = 0; u < KS; ++u) {
            const float2 f0 = *(const float2*)(xp + u * HW_);
            const float2 f1 = *(const float2*)(xp + u * HW_ + 2);
            const float2 f2 = *(const float2*)(xp + u * HW_ + 4);
            const float fv[6] = {f0.x, f0.y, f1.x, f1.y, f2.x, f2.y};
#pragma unroll
            for (int v = 0; v < KS; ++v)
                xpk[u * KS + v] = __builtin_bit_cast(h2,
                    __builtin_amdgcn_cvt_pkrtz(fv[v], fv[v + 1]));
        }
        const unsigned* kc = Kpk + (size_t)((c * OG + g) * KTAP) * 2 * OPG;
#pragma unroll
        for (int t = 0; t < KTAP; ++t) {
#pragma unroll
            for (int oi = 0; oi < OPG; ++oi) {
                const h2 nh = __builtin_bit_cast(h2, kc[t * 16 + oi]);
                const h2 nm = __builtin_bit_cast(h2, kc[t * 16 + 8 + oi]);
                hit[oi]  = __builtin_elementwise_min(xpk[t] + nh, hit[oi]);  // v_pk_add + v_pk_min
                miss[oi] = __builtin_elementwise_max(xpk[t] + nm, miss[oi]); // v_pk_add + v_pk_max
            }
        }
    }

#pragma unroll
    for (int oi = 0; oi < OPG; ++oi) {
        const h2 r = hit[oi] - miss[oi];
        const int o = g * OPG + oi;
        float* op = out + (((size_t)b * OC + o) * FH + i) * FH + j0;
        op[0] = (float)r[0];
        op[1] = (float)r[1];
    }
}

// ---------------------------------------------------------------------------
// f32 fallback (round-1 kernel, K in original (O,C,5,5) layout) — only used
// if d_ws is too small for the packed K table.
__global__ __launch_bounds__(128) void hitmiss_f32_kernel(
    const float* __restrict__ x,
    const float* __restrict__ Kh,
    const float* __restrict__ Km,
    float* __restrict__ out)
{
    const int j = threadIdx.x;
    const int i = blockIdx.x;
    const int b = blockIdx.y;
    if (j >= FH) return;

    float hit[OC], miss[OC];
#pragma unroll
    for (int o = 0; o < OC; ++o) { hit[o] = INFINITY; miss[o] = -INFINITY; }

#pragma unroll 1
    for (int c = 0; c < IC; ++c) {
        const float* xp = x + (((b * IC + c) * HW_) + i) * HW_ + j;
        float xw[KTAP];
#pragma unroll
        for (int u = 0; u < KS; ++u)
#pragma unroll
            for (int v = 0; v < KS; ++v)
                xw[u * KS + v] = xp[u * HW_ + v];
#pragma unroll
        for (int t = 0; t < KTAP - 1; t += 2) {
            const float x0 = xw[t], x1 = xw[t + 1];
#pragma unroll
            for (int o = 0; o < OC; ++o) {
                const float kh0 = Kh[(o * IC + c) * KTAP + t];
                const float kh1 = Kh[(o * IC + c) * KTAP + t + 1];
                const float km0 = Km[(o * IC + c) * KTAP + t];
                const float km1 = Km[(o * IC + c) * KTAP + t + 1];
                hit[o]  = fminf(fminf(x0 - kh0, x1 - kh1), hit[o]);
                miss[o] = fmaxf(fmaxf(x0 - km0, x1 - km1), miss[o]);
            }
        }
        {
            const float x0 = xw[KTAP - 1];
#pragma unroll
            for (int o = 0; o < OC; ++o) {
                hit[o]  = fminf(hit[o],  x0 - Kh[(o * IC + c) * KTAP + KTAP - 1]);
                miss[o] = fmaxf(miss[o], x0 - Km[(o * IC + c) * KTAP + KTAP - 1]);
            }
        }
    }

    float* op = out + ((size_t)(b * OC) * FH + i) * FH + j;
#pragma unroll
    for (int o = 0; o < OC; ++o)
        op[(size_t)o * FH * FH] = hit[o] - miss[o];
}

extern "C" void kernel_launch(void* const* d_in, const int* in_sizes, int n_in,
                              void* d_out, int out_size, void* d_ws, size_t ws_size,
                              hipStream_t stream) {
    const float* x  = (const float*)d_in[0];
    const float* Kh = (const float*)d_in[1];
    const float* Km = (const float*)d_in[2];
    float* out = (float*)d_out;

    const size_t kdwords = (size_t)IC * OG * KTAP * 2 * OPG; // 12800 dwords = 51.2 KB
    if (ws_size >= kdwords * sizeof(unsigned)) {
        unsigned* Kpk = (unsigned*)d_ws;
        pack_k_kernel<<<(int)((kdwords + 255) / 256), 256, 0, stream>>>(Kh, Km, Kpk);
        dim3 grid(FH, B_, OG);
        hitmiss_f16_kernel<<<grid, 64, 0, stream>>>(x, Kpk, out);
    } else {
        dim3 grid(FH, B_);
        hitmiss_f32_kernel<<<grid, 128, 0, stream>>>(x, Kh, Km, out);
    }
}